// Round 5
// baseline (670.157 us; speedup 1.0000x reference)
//
#include <hip/hip_runtime.h>

// Problem constants
#define Bn   16
#define Fn   48
#define Hn   256
#define Wn   256
#define Mn   51

#define TW    32
#define STRIP 16            // output rows per block
#define AROWS 22            // a-rows per block (STRIP + 6)
#define DUPR  29            // staged input rows (AROWS + 7, ky=7 pad row)
#define DUP_S 55            // dup-array row stride in dwords (odd)
#define S3    33            // out accumulator row stride
#define DUMP  (STRIP * S3)  // dump base index in s_out (64 lane slots)

// Workspace layout (floats)
#define WS_SUMSQ 0
#define WS_WN    16
#define WS_FRG   2384               // 14 tiles * 64 lanes * uint4 = 3584 floats
#define WS_TABB  5968               // 48 * 8004 ushorts = 768 KB bf16 LUT
#define TAB_N    8001
#define TAB_S    8004

typedef short short8 __attribute__((ext_vector_type(8)));
typedef float f32x4 __attribute__((ext_vector_type(4)));

__device__ __forceinline__ float waveReduceSum(float v) {
    #pragma unroll
    for (int o = 32; o > 0; o >>= 1) v += __shfl_xor(v, o);
    return v;
}

__device__ __forceinline__ unsigned short f2bf(float x) {
    unsigned int u = __builtin_bit_cast(unsigned int, x);
    unsigned int r = (u + 0x7FFFu + ((u >> 16) & 1u)) >> 16;
    return (unsigned short)r;
}

// ---- weight normalize ----
__global__ __launch_bounds__(64) void prep_kernel(const float* __restrict__ cw,
                                                  const float* __restrict__ scale_f,
                                                  float* __restrict__ ws) {
    int f = blockIdx.x;
    int t = threadIdx.x;
    float v = (t < 49) ? cw[f * 49 + t] : 0.0f;
    float mean = waveReduceSum(v) * (1.0f / 49.0f);
    float c = (t < 49) ? (v - mean) : 0.0f;
    float nrm = sqrtf(waveReduceSum(c * c));
    float o = scale_f[f] * c / (nrm + 1e-12f);
    if (t < 49) ws[WS_WN + f * 49 + t] = o;
    if (f == 0 && t < 16) ws[WS_SUMSQ + t] = 0.0f;
}

// ---- fine bf16 nearest-neighbor LUT: tab[f][i] = bf16(g_f(-100 + 0.025*i)) ----
__global__ __launch_bounds__(256) void tabb_kernel(const float* __restrict__ rw,
                                                   const float* __restrict__ rc,
                                                   float* __restrict__ ws) {
    int f = blockIdx.y;
    int idx = blockIdx.x * 256 + threadIdx.x;
    if (idx >= TAB_N) return;
    float x = -100.0f + 0.025f * (float)idx;
    float g = 0.f;
    for (int m = 0; m < Mn; ++m) {
        float d = x - rc[m];
        g += rw[f * Mn + m] * __expf(-0.01f * d * d);
    }
    unsigned short* tab = (unsigned short*)(ws + WS_TABB);
    tab[f * TAB_S + idx] = f2bf(g);
}

// ---- prebuilt MFMA weight fragments (bf16) ----
// z-GEMM A: A[m=filter][k=tap2], tap2 = ky*8+kx (K=64; kx==7 or ky==7 -> 0)
// c-GEMM A2: A2[m=tap][k=filter], tap = p*7+q (taps 49..63 zero, filters 48..63 zero)
__global__ __launch_bounds__(64) void wfrag_kernel(float* __restrict__ ws) {
    int lane = threadIdx.x;
    int quad = lane >> 4, l15 = lane & 15;
    const float* wn = ws + WS_WN;
    uint4* frg = (uint4*)(ws + WS_FRG);
    for (int mt = 0; mt < 3; ++mt)
        for (int kt = 0; kt < 2; ++kt) {
            unsigned int pk[4] = {0, 0, 0, 0};
            int f = mt * 16 + l15;
            for (int j = 0; j < 8; ++j) {
                int k = kt * 32 + quad * 8 + j;
                int ky = k >> 3, kx = k & 7;
                float v = (ky < 7 && kx < 7) ? wn[f * 49 + ky * 7 + kx] : 0.f;
                pk[j >> 1] |= (unsigned int)f2bf(v) << (16 * (j & 1));
            }
            frg[(mt * 2 + kt) * 64 + lane] = make_uint4(pk[0], pk[1], pk[2], pk[3]);
        }
    for (int mt = 0; mt < 4; ++mt)
        for (int kt = 0; kt < 2; ++kt) {
            unsigned int pk[4] = {0, 0, 0, 0};
            int tap = mt * 16 + l15;
            int p = tap / 7, q = tap - p * 7;
            for (int j = 0; j < 8; ++j) {
                int f = kt * 32 + quad * 8 + j;
                float v = (tap < 49 && f < 48) ? wn[f * 49 + (6 - p) * 7 + (6 - q)] : 0.f;
                pk[j >> 1] |= (unsigned int)f2bf(v) << (16 * (j & 1));
            }
            frg[(6 + mt * 2 + kt) * 64 + lane] = make_uint4(pk[0], pk[1], pk[2], pk[3]);
        }
}

// ---- fused MFMA kernel ----
__global__ __launch_bounds__(256) void fused_kernel(const float* __restrict__ input,
                                                    const float* __restrict__ net,
                                                    float* __restrict__ ws,
                                                    float* __restrict__ rout) {
    __shared__ unsigned int s_dup[DUPR * DUP_S];              // bf16 dup-dwords
    __shared__ __align__(16) unsigned short s_a[4][48 * 64];  // per-wave a-row [ax][f], swizzled
    __shared__ float s_out[STRIP * S3 + 64];                  // + 64 dump slots
    __shared__ float s_red[4];

    const int tid = threadIdx.x;
    const int lane = tid & 63;
    const int wv = tid >> 6;
    const int quad = lane >> 4;
    const int l15 = lane & 15;
    const int q4 = quad * 4;
    const int bz = blockIdx.z;
    const int gy0 = blockIdx.y * STRIP;
    const int tx0 = blockIdx.x * TW;
    const float* img = input + bz * (Hn * Wn);

    // stage dup array: DUPR rows x 55 dwords; dword i = (bf16 x[i], bf16 x[i+1]); symmetric pad
    for (int k = tid; k < DUPR * 55; k += 256) {
        int j = k / 55, i = k - j * 55;
        int gy = gy0 - 6 + j;
        gy = (gy < 0) ? (-1 - gy) : ((gy > 255) ? (511 - gy) : gy);
        int gx0 = tx0 - 6 + i, gx1 = gx0 + 1;
        gx0 = (gx0 < 0) ? (-1 - gx0) : ((gx0 > 255) ? (511 - gx0) : gx0);
        gx1 = (gx1 < 0) ? (-1 - gx1) : ((gx1 > 255) ? (511 - gx1) : gx1);
        float x0 = img[gy * Wn + gx0];
        float x1 = img[gy * Wn + gx1];
        s_dup[j * DUP_S + i] = (unsigned int)f2bf(x0) | ((unsigned int)f2bf(x1) << 16);
    }
    for (int k = tid; k < STRIP * S3 + 64; k += 256) s_out[k] = 0.f;
    // zero s_a filter-pad blocks (f = 48..63 -> blk 6..7) for every wave plane
    for (int k = tid; k < 4 * 48 * 2; k += 256) {
        int w = k / 96, rem = k % 96;
        int ax = rem >> 1, bb = 6 + (rem & 1);
        unsigned int off = (unsigned int)(ax * 64 + ((bb ^ (ax & 7)) * 8));
        *(uint4*)&s_a[w][off] = make_uint4(0, 0, 0, 0);
    }
    __syncthreads();

    // constant weight fragments
    const uint4* frg = (const uint4*)(ws + WS_FRG);
    short8 Afz[3][2], Afc[4][2];
    #pragma unroll
    for (int mt = 0; mt < 3; ++mt)
        #pragma unroll
        for (int kt = 0; kt < 2; ++kt)
            Afz[mt][kt] = __builtin_bit_cast(short8, frg[(mt * 2 + kt) * 64 + lane]);
    #pragma unroll
    for (int mt = 0; mt < 4; ++mt)
        #pragma unroll
        for (int kt = 0; kt < 2; ++kt)
            Afc[mt][kt] = __builtin_bit_cast(short8, frg[(6 + mt * 2 + kt) * 64 + lane]);

    // packed (p,q) per scatter element: byte = p<<3 | q
    unsigned int pq4[4];
    #pragma unroll
    for (int mt = 0; mt < 4; ++mt) {
        unsigned int v = 0;
        #pragma unroll
        for (int r = 0; r < 4; ++r) {
            int tap = mt * 16 + q4 + r;
            int tp = (tap < 49) ? tap : 48;
            int p = tp / 7, q = tp - p * 7;
            v |= (unsigned int)((p << 3) | q) << (8 * r);
        }
        pq4[mt] = v;
    }

    // LUT bases per mt (lane-dependent): f = mt*16 + q4 (+r folded at use)
    const unsigned short* tab = (const unsigned short*)(ws + WS_TABB);
    int fbase[3];
    #pragma unroll
    for (int mt = 0; mt < 3; ++mt) fbase[mt] = (mt * 16 + q4) * TAB_S;

    // per-nt column-valid masks (lane-const)
    unsigned int cvm[3];
    #pragma unroll
    for (int nt = 0; nt < 3; ++nt)
        cvm[nt] = ((unsigned)(tx0 - 3 + l15 + nt * 16) < (unsigned)Wn) ? 0xFFFFu : 0u;

    // dup row offsets: ky = kt*4 + quad
    int rowoff[2];
    rowoff[0] = quad * DUP_S + l15;
    rowoff[1] = (4 + quad) * DUP_S + l15;

    for (int ay = wv; ay < AROWS; ay += 4) {
        const int gy = gy0 - 3 + ay;
        if ((unsigned)gy >= (unsigned)Hn) continue;
        const int ayo = ay * DUP_S;

        // ---- stage 1: z GEMM + nearest-LUT -> a row (bf16) ----
        #pragma unroll
        for (int nt = 0; nt < 3; ++nt) {
            const int nt16 = nt * 16;
            short8 Bf[2];
            #pragma unroll
            for (int kt = 0; kt < 2; ++kt) {
                const unsigned int* dp = &s_dup[ayo + rowoff[kt] + nt16];
                uint4 u = make_uint4(dp[0], dp[2], dp[4], dp[6]);
                Bf[kt] = __builtin_bit_cast(short8, u);
            }
            f32x4 zacc[3];
            #pragma unroll
            for (int mt = 0; mt < 3; ++mt) {
                f32x4 z0 = {0.f, 0.f, 0.f, 0.f};
                z0 = __builtin_amdgcn_mfma_f32_16x16x32_bf16(Afz[mt][0], Bf[0], z0, 0, 0, 0);
                z0 = __builtin_amdgcn_mfma_f32_16x16x32_bf16(Afz[mt][1], Bf[1], z0, 0, 0, 0);
                zacc[mt] = z0;
            }
            const int ax = l15 + nt16;
            #pragma unroll
            for (int mt = 0; mt < 3; ++mt) {
                unsigned int pk[2] = {0, 0};
                #pragma unroll
                for (int r = 0; r < 4; ++r) {
                    float tt = fmaf(zacc[mt][r], 40.0f, 4000.5f);       // nearest: +0.5 then trunc
                    tt = fminf(fmaxf(tt, 0.f), 8000.f);
                    int i = (int)tt;
                    unsigned int v = tab[fbase[mt] + r * TAB_S + i];    // bf16 bits
                    v &= cvm[nt];
                    pk[r >> 1] |= v << (16 * (r & 1));
                }
                int blkp = (2 * mt + (quad >> 1)) ^ (ax & 7);
                unsigned int off = (unsigned int)(ax * 64 + blkp * 8 + (quad & 1) * 4);
                *(uint2*)&s_a[wv][off] = make_uint2(pk[0], pk[1]);
            }
        }

        // ---- stage 2: convT GEMM + scatter-add ----
        #pragma unroll
        for (int nt = 0; nt < 3; ++nt) {
            const int nt16 = nt * 16;
            const int ax = l15 + nt16;
            short8 B2[2];
            #pragma unroll
            for (int kt = 0; kt < 2; ++kt)
                B2[kt] = *(const short8*)&s_a[wv][ax * 64 + ((4 * kt + quad) ^ (ax & 7)) * 8];
            f32x4 d2[4];
            #pragma unroll
            for (int mt = 0; mt < 4; ++mt) {
                f32x4 c0 = {0.f, 0.f, 0.f, 0.f};
                c0 = __builtin_amdgcn_mfma_f32_16x16x32_bf16(Afc[mt][0], B2[0], c0, 0, 0, 0);
                c0 = __builtin_amdgcn_mfma_f32_16x16x32_bf16(Afc[mt][1], B2[1], c0, 0, 0, 0);
                d2[mt] = c0;
            }
            const int base = ay * S3 + ax;
            const int dumpl = DUMP + lane;
            #pragma unroll
            for (int mt = 0; mt < 4; ++mt)
                #pragma unroll
                for (int r = 0; r < 4; ++r) {
                    if (mt == 3 && r > 0) continue;          // taps 49..63 all-zero rows
                    unsigned int b = (pq4[mt] >> (8 * r)) & 255u;
                    int p = (int)(b >> 3), q = (int)(b & 7);
                    bool valid = ((unsigned)(ay - p) < (unsigned)STRIP) &&
                                 ((unsigned)(ax - q) < 32u);
                    if (mt == 3) valid = valid && (quad == 0);   // only tap 48 live
                    int idx = valid ? (base - p * S3 - q) : dumpl;
                    atomicAdd(&s_out[idx], d2[mt][r]);
                }
        }
    }

    __syncthreads();

    // epilogue: r = input - convt - net (2 px per thread)
    const float* netb = net + bz * (Hn * Wn);
    float* rb = rout + bz * (Hn * Wn);
    float rsq = 0.f;
    #pragma unroll
    for (int t = 0; t < 2; ++t) {
        const int row = (tid >> 5) * 2 + t;
        const int ox = tid & 31;
        const int gy = gy0 + row, gx = tx0 + ox;
        const float conv = s_out[row * S3 + ox];
        const float iv = img[gy * Wn + gx];
        const float r = iv - conv - netb[gy * Wn + gx];
        rb[gy * Wn + gx] = r;
        rsq += r * r;
    }
    rsq = waveReduceSum(rsq);
    if (lane == 0) s_red[wv] = rsq;
    __syncthreads();
    if (tid == 0) atomicAdd(&ws[WS_SUMSQ + bz], s_red[0] + s_red[1] + s_red[2] + s_red[3]);
}

__global__ __launch_bounds__(256) void finalize_kernel(const float* __restrict__ net,
                                                       const float* __restrict__ stdn,
                                                       const float* __restrict__ alpha,
                                                       const float* __restrict__ ws,
                                                       float* __restrict__ out) {
    const int b = blockIdx.y;
    const float sum = ws[WS_SUMSQ + b];
    const float k = __expf(alpha[0]) * stdn[b] * 256.0f;
    const float nr = sqrtf(sum);
    const float scale = fminf(1.0f, k / (nr + 1e-12f));
    const int base = b * (Hn * Wn) + (blockIdx.x * 256 + threadIdx.x) * 4;
    float4 rv = *(const float4*)(out + base);
    const float4 nv = *(const float4*)(net + base);
    float4 o;
    o.x = fmaf(rv.x, scale, nv.x);
    o.y = fmaf(rv.y, scale, nv.y);
    o.z = fmaf(rv.z, scale, nv.z);
    o.w = fmaf(rv.w, scale, nv.w);
    *(float4*)(out + base) = o;
}

extern "C" void kernel_launch(void* const* d_in, const int* in_sizes, int n_in,
                              void* d_out, int out_size, void* d_ws, size_t ws_size,
                              hipStream_t stream) {
    const float* input = (const float*)d_in[0];
    const float* stdn  = (const float*)d_in[1];
    const float* net   = (const float*)d_in[3];
    const float* cw    = (const float*)d_in[4];
    const float* sf    = (const float*)d_in[5];
    const float* alpha = (const float*)d_in[6];
    const float* rw    = (const float*)d_in[7];
    const float* rc    = (const float*)d_in[8];
    float* out = (float*)d_out;
    float* ws  = (float*)d_ws;

    prep_kernel<<<dim3(Fn), 64, 0, stream>>>(cw, sf, ws);
    tabb_kernel<<<dim3(32, Fn), 256, 0, stream>>>(rw, rc, ws);
    wfrag_kernel<<<dim3(1), 64, 0, stream>>>(ws);
    fused_kernel<<<dim3(Wn / TW, Hn / STRIP, Bn), 256, 0, stream>>>(input, net, ws, out);
    finalize_kernel<<<dim3(64, Bn), 256, 0, stream>>>(net, stdn, alpha, ws, out);
}

// Round 6
// 615.847 us; speedup vs baseline: 1.0882x; 1.0882x over previous
//
#include <hip/hip_runtime.h>

// Problem constants
#define Bn   16
#define Fn   48
#define Hn   256
#define Wn   256
#define Mn   51

#define TW    32
#define STRIP 32            // output rows per block
#define DUPR  47            // staged input rows
#define DUP_S 55            // dup-array row stride in dwords
#define SO_S  55            // s_out row stride (guard-banded)
#define SO_R  46            // s_out rows (rows -6..39 of a-space)

// Workspace layout (floats)
#define WS_SUMSQ 0
#define WS_WN    16
#define WS_FRG   2384               // 14 tiles * 64 lanes * uint4 = 3584 floats
#define WS_TABB  5968               // 48 * 8004 ushorts bf16 LUT
#define TAB_N    8001
#define TAB_S    8004

typedef short short8 __attribute__((ext_vector_type(8)));
typedef float f32x4 __attribute__((ext_vector_type(4)));

__device__ __forceinline__ float waveReduceSum(float v) {
    #pragma unroll
    for (int o = 32; o > 0; o >>= 1) v += __shfl_xor(v, o);
    return v;
}

__device__ __forceinline__ unsigned short f2bf(float x) {
    unsigned int u = __builtin_bit_cast(unsigned int, x);
    unsigned int r = (u + 0x7FFFu + ((u >> 16) & 1u)) >> 16;
    return (unsigned short)r;
}

// ---- weight normalize ----
__global__ __launch_bounds__(64) void prep_kernel(const float* __restrict__ cw,
                                                  const float* __restrict__ scale_f,
                                                  float* __restrict__ ws) {
    int f = blockIdx.x;
    int t = threadIdx.x;
    float v = (t < 49) ? cw[f * 49 + t] : 0.0f;
    float mean = waveReduceSum(v) * (1.0f / 49.0f);
    float c = (t < 49) ? (v - mean) : 0.0f;
    float nrm = sqrtf(waveReduceSum(c * c));
    float o = scale_f[f] * c / (nrm + 1e-12f);
    if (t < 49) ws[WS_WN + f * 49 + t] = o;
    if (f == 0 && t < 16) ws[WS_SUMSQ + t] = 0.0f;
}

// ---- fine bf16 nearest-neighbor LUT: tab[f][i] = bf16(g_f(-100 + 0.025*i)) ----
__global__ __launch_bounds__(256) void tabb_kernel(const float* __restrict__ rw,
                                                   const float* __restrict__ rc,
                                                   float* __restrict__ ws) {
    int f = blockIdx.y;
    int idx = blockIdx.x * 256 + threadIdx.x;
    if (idx >= TAB_N) return;
    float x = -100.0f + 0.025f * (float)idx;
    float g = 0.f;
    for (int m = 0; m < Mn; ++m) {
        float d = x - rc[m];
        g += rw[f * Mn + m] * __expf(-0.01f * d * d);
    }
    unsigned short* tab = (unsigned short*)(ws + WS_TABB);
    tab[f * TAB_S + idx] = f2bf(g);
}

// ---- prebuilt MFMA weight fragments (bf16) ----
__global__ __launch_bounds__(64) void wfrag_kernel(float* __restrict__ ws) {
    int lane = threadIdx.x;
    int quad = lane >> 4, l15 = lane & 15;
    const float* wn = ws + WS_WN;
    uint4* frg = (uint4*)(ws + WS_FRG);
    for (int mt = 0; mt < 3; ++mt)
        for (int kt = 0; kt < 2; ++kt) {
            unsigned int pk[4] = {0, 0, 0, 0};
            int f = mt * 16 + l15;
            for (int j = 0; j < 8; ++j) {
                int k = kt * 32 + quad * 8 + j;
                int ky = k >> 3, kx = k & 7;
                float v = (ky < 7 && kx < 7) ? wn[f * 49 + ky * 7 + kx] : 0.f;
                pk[j >> 1] |= (unsigned int)f2bf(v) << (16 * (j & 1));
            }
            frg[(mt * 2 + kt) * 64 + lane] = make_uint4(pk[0], pk[1], pk[2], pk[3]);
        }
    for (int mt = 0; mt < 4; ++mt)
        for (int kt = 0; kt < 2; ++kt) {
            unsigned int pk[4] = {0, 0, 0, 0};
            int tap = mt * 16 + l15;
            int p = tap / 7, q = tap - p * 7;
            for (int j = 0; j < 8; ++j) {
                int f = kt * 32 + quad * 8 + j;
                float v = (tap < 49 && f < 48) ? wn[f * 49 + (6 - p) * 7 + (6 - q)] : 0.f;
                pk[j >> 1] |= (unsigned int)f2bf(v) << (16 * (j & 1));
            }
            frg[(6 + mt * 2 + kt) * 64 + lane] = make_uint4(pk[0], pk[1], pk[2], pk[3]);
        }
}

struct Unit {
    unsigned g[12];   // pending LUT gathers (bf16 bits, zero-extended)
    int base;         // s_out scatter base index
    unsigned mask;    // 0xFFFF if (gy,gx) valid else 0
};

// ---- fused MFMA kernel, software-pipelined over (row, nt) units ----
__global__ __launch_bounds__(256) void fused_kernel(const float* __restrict__ input,
                                                    const float* __restrict__ net,
                                                    float* __restrict__ ws,
                                                    float* __restrict__ rout) {
    __shared__ unsigned int s_dup[DUPR * DUP_S];              // bf16 dup-dwords
    __shared__ __align__(16) unsigned short s_a[4][16 * 64];  // per-wave 16-col a-slice
    __shared__ float s_out[SO_R * SO_S];                      // guard-banded accumulator
    __shared__ float s_red[4];

    const int tid = threadIdx.x;
    const int lane = tid & 63;
    const int wv = tid >> 6;
    const int quad = lane >> 4;
    const int l15 = lane & 15;
    const int q4 = quad * 4;
    const int bz = blockIdx.z;
    const int gy0 = blockIdx.y * STRIP;
    const int tx0 = blockIdx.x * TW;
    const float* img = input + bz * (Hn * Wn);

    // stage dup array: 47 rows x 55 dwords; dword i = (bf16 x[i], bf16 x[i+1]); symmetric pad
    for (int k = tid; k < DUPR * DUP_S; k += 256) {
        int j = k / DUP_S, i = k - j * DUP_S;
        int gy = gy0 - 6 + j;
        gy = (gy < 0) ? (-1 - gy) : ((gy > 255) ? (511 - gy) : gy);
        int gx0 = tx0 - 6 + i, gx1 = gx0 + 1;
        gx0 = (gx0 < 0) ? (-1 - gx0) : ((gx0 > 255) ? (511 - gx0) : gx0);
        gx1 = (gx1 < 0) ? (-1 - gx1) : ((gx1 > 255) ? (511 - gx1) : gx1);
        float x0 = img[gy * Wn + gx0];
        float x1 = img[gy * Wn + gx1];
        s_dup[j * DUP_S + i] = (unsigned int)f2bf(x0) | ((unsigned int)f2bf(x1) << 16);
    }
    for (int k = tid; k < SO_R * SO_S; k += 256) s_out[k] = 0.f;
    __syncthreads();

    // constant weight fragments
    const uint4* frg = (const uint4*)(ws + WS_FRG);
    short8 Afz[3][2], Afc[4][2];
    #pragma unroll
    for (int mt = 0; mt < 3; ++mt)
        #pragma unroll
        for (int kt = 0; kt < 2; ++kt)
            Afz[mt][kt] = __builtin_bit_cast(short8, frg[(mt * 2 + kt) * 64 + lane]);
    #pragma unroll
    for (int mt = 0; mt < 4; ++mt)
        #pragma unroll
        for (int kt = 0; kt < 2; ++kt)
            Afc[mt][kt] = __builtin_bit_cast(short8, frg[(6 + mt * 2 + kt) * 64 + lane]);

    // scatter offsets (lane-const): e = mt*4+r (mt<3) + e=12 (tap 48)
    int offD[13];
    #pragma unroll
    for (int mt = 0; mt < 3; ++mt)
        #pragma unroll
        for (int r = 0; r < 4; ++r) {
            int tap = mt * 16 + q4 + r;
            int p = tap / 7, q = tap - p * 7;
            offD[mt * 4 + r] = -(p * SO_S + q);
        }
    offD[12] = -(6 * SO_S + 6);   // tap 48 (quads>0 contribute zeros)

    const unsigned short* tab = (const unsigned short*)(ws + WS_TABB);
    const int fq = q4 * TAB_S;                 // lane part of LUT filter base
    const int dOff = quad * DUP_S + l15;       // dup lane offset
    const int gx0l = tx0 - 3 + l15;            // lane x for validity
    const int bcol = l15 + 6 * SO_S + 6;       // lane part of scatter base

    // s_a slice addresses (shorts)
    unsigned short* sa = s_a[wv];
    int wOff[3], rOff[2];
    #pragma unroll
    for (int mt = 0; mt < 3; ++mt)
        wOff[mt] = l15 * 64 + (((2 * mt + (quad >> 1)) ^ (l15 & 7)) * 8) + (quad & 1) * 4;
    #pragma unroll
    for (int kt = 0; kt < 2; ++kt)
        rOff[kt] = l15 * 64 + (((4 * kt + quad) ^ (l15 & 7)) * 8);

    auto S1 = [&](int ay, int nt16, Unit& U) {
        const unsigned* dp0 = &s_dup[ay * DUP_S + nt16 + dOff];
        const unsigned* dp1 = dp0 + 4 * DUP_S;
        uint4 u0 = make_uint4(dp0[0], dp0[2], dp0[4], dp0[6]);
        uint4 u1 = make_uint4(dp1[0], dp1[2], dp1[4], dp1[6]);
        short8 B0 = __builtin_bit_cast(short8, u0);
        short8 B1 = __builtin_bit_cast(short8, u1);
        #pragma unroll
        for (int mt = 0; mt < 3; ++mt) {
            f32x4 z = {0.f, 0.f, 0.f, 0.f};
            z = __builtin_amdgcn_mfma_f32_16x16x32_bf16(Afz[mt][0], B0, z, 0, 0, 0);
            z = __builtin_amdgcn_mfma_f32_16x16x32_bf16(Afz[mt][1], B1, z, 0, 0, 0);
            #pragma unroll
            for (int r = 0; r < 4; ++r) {
                float tt = fmaf(z[r], 40.0f, 4000.5f);
                tt = fminf(fmaxf(tt, 0.f), 8000.f);
                int i = (int)tt;
                U.g[mt * 4 + r] = tab[fq + (mt * 16 + r) * TAB_S + i];
            }
        }
        bool vy = ((unsigned)(gy0 - 3 + ay) < (unsigned)Hn);
        bool vx = ((unsigned)(gx0l + nt16) < (unsigned)Wn);
        U.mask = (vy && vx) ? 0xFFFFu : 0u;
        U.base = ay * SO_S + nt16 + bcol;
    };

    auto S2 = [&](const Unit& U) {
        const unsigned m = U.mask;
        #pragma unroll
        for (int mt = 0; mt < 3; ++mt) {
            unsigned lo = (U.g[mt * 4 + 0] & m) | ((U.g[mt * 4 + 1] & m) << 16);
            unsigned hi = (U.g[mt * 4 + 2] & m) | ((U.g[mt * 4 + 3] & m) << 16);
            *(uint2*)&sa[wOff[mt]] = make_uint2(lo, hi);
        }
        short8 B20 = *(const short8*)&sa[rOff[0]];
        short8 B21 = *(const short8*)&sa[rOff[1]];
        f32x4 d2[4];
        #pragma unroll
        for (int mt = 0; mt < 4; ++mt) {
            f32x4 c0 = {0.f, 0.f, 0.f, 0.f};
            c0 = __builtin_amdgcn_mfma_f32_16x16x32_bf16(Afc[mt][0], B20, c0, 0, 0, 0);
            c0 = __builtin_amdgcn_mfma_f32_16x16x32_bf16(Afc[mt][1], B21, c0, 0, 0, 0);
            d2[mt] = c0;
        }
        #pragma unroll
        for (int mt = 0; mt < 3; ++mt)
            #pragma unroll
            for (int r = 0; r < 4; ++r)
                atomicAdd(&s_out[U.base + offD[mt * 4 + r]], d2[mt][r]);
        atomicAdd(&s_out[U.base + offD[12]], d2[3][0]);
    };

    // pipelined unit loop: 10 rows x 3 nt per wave (rows ay = wv + 4*ri; dummies masked/absorbed)
    Unit cur, nxt;
    int ay = wv, nt16 = 0;
    S1(ay, nt16, cur);
    for (int u = 0; u < 30; ++u) {
        int ay2 = ay, nt2 = nt16 + 16;
        if (nt2 == 48) { nt2 = 0; ay2 = ay + 4; }
        if (u < 29) S1(ay2, nt2, nxt);
        S2(cur);
        cur = nxt; ay = ay2; nt16 = nt2;
    }

    __syncthreads();

    // epilogue: r = input - convt - net (4 px per thread)
    const float* netb = net + bz * (Hn * Wn);
    float* rb = rout + bz * (Hn * Wn);
    float rsq = 0.f;
    #pragma unroll
    for (int t = 0; t < 4; ++t) {
        const int row = wv * 8 + (lane >> 5) + t * 2;
        const int ox = lane & 31;
        const int gy = gy0 + row, gx = tx0 + ox;
        const float conv = s_out[(row + 6) * SO_S + ox + 6];
        const float iv = img[gy * Wn + gx];
        const float r = iv - conv - netb[gy * Wn + gx];
        rb[gy * Wn + gx] = r;
        rsq += r * r;
    }
    rsq = waveReduceSum(rsq);
    if (lane == 0) s_red[wv] = rsq;
    __syncthreads();
    if (tid == 0) atomicAdd(&ws[WS_SUMSQ + bz], s_red[0] + s_red[1] + s_red[2] + s_red[3]);
}

__global__ __launch_bounds__(256) void finalize_kernel(const float* __restrict__ net,
                                                       const float* __restrict__ stdn,
                                                       const float* __restrict__ alpha,
                                                       const float* __restrict__ ws,
                                                       float* __restrict__ out) {
    const int b = blockIdx.y;
    const float sum = ws[WS_SUMSQ + b];
    const float k = __expf(alpha[0]) * stdn[b] * 256.0f;
    const float nr = sqrtf(sum);
    const float scale = fminf(1.0f, k / (nr + 1e-12f));
    const int base = b * (Hn * Wn) + (blockIdx.x * 256 + threadIdx.x) * 4;
    float4 rv = *(const float4*)(out + base);
    const float4 nv = *(const float4*)(net + base);
    float4 o;
    o.x = fmaf(rv.x, scale, nv.x);
    o.y = fmaf(rv.y, scale, nv.y);
    o.z = fmaf(rv.z, scale, nv.z);
    o.w = fmaf(rv.w, scale, nv.w);
    *(float4*)(out + base) = o;
}

extern "C" void kernel_launch(void* const* d_in, const int* in_sizes, int n_in,
                              void* d_out, int out_size, void* d_ws, size_t ws_size,
                              hipStream_t stream) {
    const float* input = (const float*)d_in[0];
    const float* stdn  = (const float*)d_in[1];
    const float* net   = (const float*)d_in[3];
    const float* cw    = (const float*)d_in[4];
    const float* sf    = (const float*)d_in[5];
    const float* alpha = (const float*)d_in[6];
    const float* rw    = (const float*)d_in[7];
    const float* rc    = (const float*)d_in[8];
    float* out = (float*)d_out;
    float* ws  = (float*)d_ws;

    prep_kernel<<<dim3(Fn), 64, 0, stream>>>(cw, sf, ws);
    tabb_kernel<<<dim3(32, Fn), 256, 0, stream>>>(rw, rc, ws);
    wfrag_kernel<<<dim3(1), 64, 0, stream>>>(ws);
    fused_kernel<<<dim3(Wn / TW, Hn / STRIP, Bn), 256, 0, stream>>>(input, net, ws, out);
    finalize_kernel<<<dim3(64, Bn), 256, 0, stream>>>(net, stdn, alpha, ws, out);
}

// Round 7
// 221.316 us; speedup vs baseline: 3.0281x; 2.7827x over previous
//
#include <hip/hip_runtime.h>

// Problem constants
#define Bn   16
#define Fn   48
#define Hn   256
#define Wn   256
#define Mn   51

#define TW    32
#define STRIP 32
#define DUPR  45
#define DUP_S 55            // dup-array row stride in dwords
#define C2S   50            // C2 ax-stride (dwords); taps rows 0..49

// Workspace layout (floats)
#define WS_SUMSQ 0
#define WS_WN    16
#define WS_FRG   2384               // 14 tiles * 64 lanes * uint4
#define WS_TABB  5968               // 48 * 8004 ushorts bf16 LUT
#define TAB_N    8001
#define TAB_S    8004

typedef short short8 __attribute__((ext_vector_type(8)));
typedef float f32x4 __attribute__((ext_vector_type(4)));

__device__ __forceinline__ float waveReduceSum(float v) {
    #pragma unroll
    for (int o = 32; o > 0; o >>= 1) v += __shfl_xor(v, o);
    return v;
}

__device__ __forceinline__ unsigned short f2bf(float x) {
    unsigned int u = __builtin_bit_cast(unsigned int, x);
    unsigned int r = (u + 0x7FFFu + ((u >> 16) & 1u)) >> 16;
    return (unsigned short)r;
}

// ---- weight normalize ----
__global__ __launch_bounds__(64) void prep_kernel(const float* __restrict__ cw,
                                                  const float* __restrict__ scale_f,
                                                  float* __restrict__ ws) {
    int f = blockIdx.x;
    int t = threadIdx.x;
    float v = (t < 49) ? cw[f * 49 + t] : 0.0f;
    float mean = waveReduceSum(v) * (1.0f / 49.0f);
    float c = (t < 49) ? (v - mean) : 0.0f;
    float nrm = sqrtf(waveReduceSum(c * c));
    float o = scale_f[f] * c / (nrm + 1e-12f);
    if (t < 49) ws[WS_WN + f * 49 + t] = o;
    if (f == 0 && t < 16) ws[WS_SUMSQ + t] = 0.0f;
}

// ---- fine bf16 nearest-neighbor LUT ----
__global__ __launch_bounds__(256) void tabb_kernel(const float* __restrict__ rw,
                                                   const float* __restrict__ rc,
                                                   float* __restrict__ ws) {
    int f = blockIdx.y;
    int idx = blockIdx.x * 256 + threadIdx.x;
    if (idx >= TAB_N) return;
    float x = -100.0f + 0.025f * (float)idx;
    float g = 0.f;
    for (int m = 0; m < Mn; ++m) {
        float d = x - rc[m];
        g += rw[f * Mn + m] * __expf(-0.01f * d * d);
    }
    unsigned short* tab = (unsigned short*)(ws + WS_TABB);
    tab[f * TAB_S + idx] = f2bf(g);
}

// ---- prebuilt MFMA weight fragments (bf16) ----
__global__ __launch_bounds__(64) void wfrag_kernel(float* __restrict__ ws) {
    int lane = threadIdx.x;
    int quad = lane >> 4, l15 = lane & 15;
    const float* wn = ws + WS_WN;
    uint4* frg = (uint4*)(ws + WS_FRG);
    for (int mt = 0; mt < 3; ++mt)
        for (int kt = 0; kt < 2; ++kt) {
            unsigned int pk[4] = {0, 0, 0, 0};
            int f = mt * 16 + l15;
            for (int j = 0; j < 8; ++j) {
                int k = kt * 32 + quad * 8 + j;
                int ky = k >> 3, kx = k & 7;
                float v = (ky < 7 && kx < 7) ? wn[f * 49 + ky * 7 + kx] : 0.f;
                pk[j >> 1] |= (unsigned int)f2bf(v) << (16 * (j & 1));
            }
            frg[(mt * 2 + kt) * 64 + lane] = make_uint4(pk[0], pk[1], pk[2], pk[3]);
        }
    for (int mt = 0; mt < 4; ++mt)
        for (int kt = 0; kt < 2; ++kt) {
            unsigned int pk[4] = {0, 0, 0, 0};
            int tap = mt * 16 + l15;
            int p = tap / 7, q = tap - p * 7;
            for (int j = 0; j < 8; ++j) {
                int f = kt * 32 + quad * 8 + j;
                float v = (tap < 49 && f < 48) ? wn[f * 49 + (6 - p) * 7 + (6 - q)] : 0.f;
                pk[j >> 1] |= (unsigned int)f2bf(v) << (16 * (j & 1));
            }
            frg[(6 + mt * 2 + kt) * 64 + lane] = make_uint4(pk[0], pk[1], pk[2], pk[3]);
        }
}

// ---- fused MFMA kernel: per-wave 8-row band, register sliding window, no atomics ----
__global__ __launch_bounds__(256) void fused_kernel(const float* __restrict__ input,
                                                    const float* __restrict__ net,
                                                    float* __restrict__ ws,
                                                    float* __restrict__ rout) {
    __shared__ unsigned int s_dup[DUPR * DUP_S];
    __shared__ __align__(16) unsigned short s_a[4][16 * 64];
    __shared__ float s_c2[4][50 * C2S];      // per-wave [tap][ax]
    __shared__ float s_red[4];

    const int tid = threadIdx.x;
    const int lane = tid & 63;
    const int wv = tid >> 6;
    const int quad = lane >> 4;
    const int l15 = lane & 15;
    const int q4 = quad * 4;
    const int hl = lane >> 5;
    const int OX = lane & 31;
    const int bz = blockIdx.z;
    const int gy0 = blockIdx.y * STRIP;
    const int tx0 = blockIdx.x * TW;
    const float* img = input + bz * (Hn * Wn);
    const float* netb = net + bz * (Hn * Wn);
    float* rb = rout + bz * (Hn * Wn);

    // stage dup array: 45 rows x 55 dwords; dword i = (bf16 x[i], bf16 x[i+1]); sym pad
    for (int k = tid; k < DUPR * DUP_S; k += 256) {
        int j = k / DUP_S, i = k - j * DUP_S;
        int gy = gy0 - 6 + j;
        gy = (gy < 0) ? (-1 - gy) : ((gy > 255) ? (511 - gy) : gy);
        int gx0 = tx0 - 6 + i, gx1 = gx0 + 1;
        gx0 = (gx0 < 0) ? (-1 - gx0) : ((gx0 > 255) ? (511 - gx0) : gx0);
        gx1 = (gx1 < 0) ? (-1 - gx1) : ((gx1 > 255) ? (511 - gx1) : gx1);
        float x0 = img[gy * Wn + gx0];
        float x1 = img[gy * Wn + gx1];
        s_dup[j * DUP_S + i] = (unsigned int)f2bf(x0) | ((unsigned int)f2bf(x1) << 16);
    }
    __syncthreads();

    // constant weight fragments
    const uint4* frg = (const uint4*)(ws + WS_FRG);
    short8 Afz[3][2], Afc[4][2];
    #pragma unroll
    for (int mt = 0; mt < 3; ++mt)
        #pragma unroll
        for (int kt = 0; kt < 2; ++kt)
            Afz[mt][kt] = __builtin_bit_cast(short8, frg[(mt * 2 + kt) * 64 + lane]);
    #pragma unroll
    for (int mt = 0; mt < 4; ++mt)
        #pragma unroll
        for (int kt = 0; kt < 2; ++kt)
            Afc[mt][kt] = __builtin_bit_cast(short8, frg[(6 + mt * 2 + kt) * 64 + lane]);

    const unsigned short* tab = (const unsigned short*)(ws + WS_TABB);
    const int fq = q4 * TAB_S;
    unsigned short* sa = s_a[wv];
    float* c2w = s_c2[wv];
    int wOff[3], rOff[2];
    #pragma unroll
    for (int mt = 0; mt < 3; ++mt)
        wOff[mt] = l15 * 64 + (((2 * mt + (quad >> 1)) ^ (l15 & 7)) * 8) + (quad & 1) * 4;
    #pragma unroll
    for (int kt = 0; kt < 2; ++kt)
        rOff[kt] = l15 * 64 + (((4 * kt + quad) ^ (l15 & 7)) * 8);

    const int A0 = wv * 8;
    float w[4] = {0.f, 0.f, 0.f, 0.f};
    float rsq = 0.f;

    // one a-row sub-iteration; `even` is compile-time (two inlined bodies)
    auto subiter = [&](int i, bool even) {
        const int aIdx = A0 + i;
        const int gyz = gy0 - 3 + aIdx;
        const bool vy = ((unsigned)gyz < (unsigned)Hn);

        #pragma unroll
        for (int nt = 0; nt < 3; ++nt) {
            const int nt16 = nt * 16;
            const int ax = l15 + nt16;
            // B-frags from dup rows aIdx+ky
            const unsigned* dp0 = &s_dup[(aIdx + quad) * DUP_S + l15 + nt16];
            const unsigned* dp1 = dp0 + 4 * DUP_S;
            short8 B0 = __builtin_bit_cast(short8, make_uint4(dp0[0], dp0[2], dp0[4], dp0[6]));
            short8 B1 = __builtin_bit_cast(short8, make_uint4(dp1[0], dp1[2], dp1[4], dp1[6]));
            // z GEMM + nearest LUT + pack -> s_a slice
            const unsigned msk = (vy && ((unsigned)(tx0 - 3 + ax) < (unsigned)Wn))
                                 ? 0xFFFFFFFFu : 0u;
            #pragma unroll
            for (int mt = 0; mt < 3; ++mt) {
                f32x4 z = {0.f, 0.f, 0.f, 0.f};
                z = __builtin_amdgcn_mfma_f32_16x16x32_bf16(Afz[mt][0], B0, z, 0, 0, 0);
                z = __builtin_amdgcn_mfma_f32_16x16x32_bf16(Afz[mt][1], B1, z, 0, 0, 0);
                unsigned g[4];
                #pragma unroll
                for (int r = 0; r < 4; ++r) {
                    float tt = fmaf(z[r], 40.0f, 4000.5f);
                    tt = fminf(fmaxf(tt, 0.f), 8000.f);
                    g[r] = tab[fq + (mt * 16 + r) * TAB_S + (int)tt];
                }
                unsigned lo = (g[0] | (g[1] << 16)) & msk;
                unsigned hi = (g[2] | (g[3] << 16)) & msk;
                *(uint2*)&sa[wOff[mt]] = make_uint2(lo, hi);
            }
            // convT GEMM
            short8 B20 = *(const short8*)&sa[rOff[0]];
            short8 B21 = *(const short8*)&sa[rOff[1]];
            f32x4 d2[4];
            #pragma unroll
            for (int mt = 0; mt < 4; ++mt) {
                f32x4 c0 = {0.f, 0.f, 0.f, 0.f};
                c0 = __builtin_amdgcn_mfma_f32_16x16x32_bf16(Afc[mt][0], B20, c0, 0, 0, 0);
                c0 = __builtin_amdgcn_mfma_f32_16x16x32_bf16(Afc[mt][1], B21, c0, 0, 0, 0);
                d2[mt] = c0;
            }
            // C2 stores (plain b32, per-wave private)
            #pragma unroll
            for (int mt = 0; mt < 3; ++mt)
                #pragma unroll
                for (int r = 0; r < 4; ++r)
                    c2w[(mt * 16 + q4 + r) * C2S + ax] = d2[mt][r];
            {
                int tp = 48 + q4; if (tp > 49) tp = 49;   // quads>0 -> junk row 49
                c2w[tp * C2S + ax] = d2[3][0];
            }
        }

        // ---- q-gather into register window (same wave, in-order LDS) ----
        const bool laneE = even ? (hl == 0) : (hl != 0);
        #pragma unroll
        for (int j = 0; j < 4; ++j) {
            const int pe = 2 * j, po = 2 * j + 1;
            const bool liveE = (pe <= i) && (pe >= i - 7);
            const bool liveO = (j < 3) && (po <= i) && (po >= i - 7);
            if (liveE || liveO) {
                int psel = laneE ? pe : po;
                if (!liveO) psel = pe;
                if (!liveE) psel = po;
                const int tb = psel * 7 * C2S;
                #pragma unroll
                for (int q = 0; q < 7; ++q) {
                    float s = c2w[tb + q * C2S + OX + q];
                    if (liveE) w[3 - j] += laneE ? s : 0.f;
                    if (liveO) w[2 - j] += laneE ? 0.f : s;
                }
            }
        }

        // ---- close one output row + shift window ----
        if (i >= 6) {
            const int gyO = gy0 + A0 + i - 6;
            const int o = gyO * Wn + tx0 + OX;
            if (laneE) {
                float r = img[o] - w[0] - netb[o];
                rb[o] = r;
                rsq += r * r;
            }
        }
        w[0] = laneE ? w[1] : w[0];
        w[1] = laneE ? w[2] : w[1];
        w[2] = laneE ? w[3] : w[2];
        w[3] = laneE ? 0.f : w[3];
    };

    #pragma unroll 1
    for (int mi = 0; mi < 7; ++mi) {
        subiter(2 * mi, true);
        subiter(2 * mi + 1, false);
    }

    rsq = waveReduceSum(rsq);
    if (lane == 0) s_red[wv] = rsq;
    __syncthreads();
    if (tid == 0) atomicAdd(&ws[WS_SUMSQ + bz], s_red[0] + s_red[1] + s_red[2] + s_red[3]);
}

__global__ __launch_bounds__(256) void finalize_kernel(const float* __restrict__ net,
                                                       const float* __restrict__ stdn,
                                                       const float* __restrict__ alpha,
                                                       const float* __restrict__ ws,
                                                       float* __restrict__ out) {
    const int b = blockIdx.y;
    const float sum = ws[WS_SUMSQ + b];
    const float k = __expf(alpha[0]) * stdn[b] * 256.0f;
    const float nr = sqrtf(sum);
    const float scale = fminf(1.0f, k / (nr + 1e-12f));
    const int base = b * (Hn * Wn) + (blockIdx.x * 256 + threadIdx.x) * 4;
    float4 rv = *(const float4*)(out + base);
    const float4 nv = *(const float4*)(net + base);
    float4 o;
    o.x = fmaf(rv.x, scale, nv.x);
    o.y = fmaf(rv.y, scale, nv.y);
    o.z = fmaf(rv.z, scale, nv.z);
    o.w = fmaf(rv.w, scale, nv.w);
    *(float4*)(out + base) = o;
}

extern "C" void kernel_launch(void* const* d_in, const int* in_sizes, int n_in,
                              void* d_out, int out_size, void* d_ws, size_t ws_size,
                              hipStream_t stream) {
    const float* input = (const float*)d_in[0];
    const float* stdn  = (const float*)d_in[1];
    const float* net   = (const float*)d_in[3];
    const float* cw    = (const float*)d_in[4];
    const float* sf    = (const float*)d_in[5];
    const float* alpha = (const float*)d_in[6];
    const float* rw    = (const float*)d_in[7];
    const float* rc    = (const float*)d_in[8];
    float* out = (float*)d_out;
    float* ws  = (float*)d_ws;

    prep_kernel<<<dim3(Fn), 64, 0, stream>>>(cw, sf, ws);
    tabb_kernel<<<dim3(32, Fn), 256, 0, stream>>>(rw, rc, ws);
    wfrag_kernel<<<dim3(1), 64, 0, stream>>>(ws);
    fused_kernel<<<dim3(Wn / TW, Hn / STRIP, Bn), 256, 0, stream>>>(input, net, ws, out);
    finalize_kernel<<<dim3(64, Bn), 256, 0, stream>>>(net, stdn, alpha, ws, out);
}

// Round 9
// 197.691 us; speedup vs baseline: 3.3899x; 1.1195x over previous
//
#include <hip/hip_runtime.h>

// Problem constants
#define Bn   16
#define Fn   48
#define Hn   256
#define Wn   256
#define Mn   51

#define TW    32
#define STRIP 32
#define DUPR  45
#define DUP_S 55            // dup-array row stride in dwords
#define C2ST  58            // c2 row stride in shorts (dword stride 29, odd -> bank spread)
#define C2DW  29

// Workspace layout (floats)
#define WS_SUMSQ 0
#define WS_FRG   16                 // 14 tiles * 64 lanes * uint4 = 3584 floats
#define WS_TABB  3600               // 48 * 8004 ushorts bf16 LUT
#define TAB_N    8001
#define TAB_S    8004

typedef short short8 __attribute__((ext_vector_type(8)));
typedef float f32x4 __attribute__((ext_vector_type(4)));

__device__ __forceinline__ float waveReduceSum(float v) {
    #pragma unroll
    for (int o = 32; o > 0; o >>= 1) v += __shfl_xor(v, o);
    return v;
}

__device__ __forceinline__ unsigned short f2bf(float x) {
    unsigned int u = __builtin_bit_cast(unsigned int, x);
    unsigned int r = (u + 0x7FFFu + ((u >> 16) & 1u)) >> 16;
    return (unsigned short)r;
}

// ---- single setup kernel: block 0 = weight prep + MFMA fragments; blocks 1.. = RBF LUT ----
__global__ __launch_bounds__(256) void setup_kernel(const float* __restrict__ cw,
                                                    const float* __restrict__ sf,
                                                    const float* __restrict__ rw,
                                                    const float* __restrict__ rc,
                                                    float* __restrict__ ws) {
    const int tid = threadIdx.x;
    if (blockIdx.x == 0) {
        __shared__ float s_wn[Fn * 49];
        const int lane = tid & 63;
        const int wv = tid >> 6;
        for (int i = 0; i < 12; ++i) {
            int f = wv * 12 + i;
            float v = (lane < 49) ? cw[f * 49 + lane] : 0.f;
            float mean = waveReduceSum(v) * (1.0f / 49.0f);
            float c = (lane < 49) ? (v - mean) : 0.f;
            float nrm = sqrtf(waveReduceSum(c * c));
            if (lane < 49) s_wn[f * 49 + lane] = sf[f] * c / (nrm + 1e-12f);
        }
        if (tid < 16) ws[WS_SUMSQ + tid] = 0.f;
        __syncthreads();
        if (wv == 0) {
            const int quad = lane >> 4, l15 = lane & 15;
            uint4* frg = (uint4*)(ws + WS_FRG);
            // z-GEMM A: A[m=filter][k=tap2], tap2 = ky*8+kx
            for (int mt = 0; mt < 3; ++mt)
                for (int kt = 0; kt < 2; ++kt) {
                    unsigned int pk[4] = {0, 0, 0, 0};
                    int f = mt * 16 + l15;
                    for (int j = 0; j < 8; ++j) {
                        int k = kt * 32 + quad * 8 + j;
                        int ky = k >> 3, kx = k & 7;
                        float v = (ky < 7 && kx < 7) ? s_wn[f * 49 + ky * 7 + kx] : 0.f;
                        pk[j >> 1] |= (unsigned int)f2bf(v) << (16 * (j & 1));
                    }
                    frg[(mt * 2 + kt) * 64 + lane] = make_uint4(pk[0], pk[1], pk[2], pk[3]);
                }
            // c-GEMM A2: A2[m][k=filter], m = p*8+q (q==7 or m>=56 -> zero row)
            for (int mt = 0; mt < 4; ++mt)
                for (int kt = 0; kt < 2; ++kt) {
                    unsigned int pk[4] = {0, 0, 0, 0};
                    int m = mt * 16 + l15;
                    int p = m >> 3, q = m & 7;
                    for (int j = 0; j < 8; ++j) {
                        int f = kt * 32 + quad * 8 + j;
                        float v = (p < 7 && q < 7 && f < 48)
                                  ? s_wn[f * 49 + (6 - p) * 7 + (6 - q)] : 0.f;
                        pk[j >> 1] |= (unsigned int)f2bf(v) << (16 * (j & 1));
                    }
                    frg[(6 + mt * 2 + kt) * 64 + lane] = make_uint4(pk[0], pk[1], pk[2], pk[3]);
                }
        }
    } else {
        int b = blockIdx.x - 1;
        int f = b >> 5;
        int idx = ((b & 31) << 8) + tid;
        if (idx < TAB_N) {
            float x = -100.0f + 0.025f * (float)idx;
            float g = 0.f;
            for (int m = 0; m < Mn; ++m) {
                float d = x - rc[m];
                g += rw[f * Mn + m] * __expf(-0.01f * d * d);
            }
            unsigned short* tab = (unsigned short*)(ws + WS_TABB);
            tab[f * TAB_S + idx] = f2bf(g);
        }
    }
}

// ---- fused MFMA kernel: per-wave 8-row band, register sliding window, bf16 C2 ----
__global__ __launch_bounds__(256) void fused_kernel(const float* __restrict__ input,
                                                    const float* __restrict__ net,
                                                    float* __restrict__ ws,
                                                    float* __restrict__ rout) {
    __shared__ unsigned int s_dup[DUPR * DUP_S];
    __shared__ __align__(16) unsigned short s_a[4][16 * 64];
    __shared__ __align__(8) unsigned short s_c2[4][48 * C2ST];   // per-wave [ax][m=p*8+q] bf16
    __shared__ float s_red[4];

    const int tid = threadIdx.x;
    const int lane = tid & 63;
    const int wv = tid >> 6;
    const int quad = lane >> 4;
    const int l15 = lane & 15;
    const int q4 = quad * 4;
    const int hl = lane >> 5;
    const int OX = lane & 31;
    const int bz = blockIdx.z;
    const int gy0 = blockIdx.y * STRIP;
    const int tx0 = blockIdx.x * TW;
    const float* img = input + bz * (Hn * Wn);
    const float* netb = net + bz * (Hn * Wn);
    float* rb = rout + bz * (Hn * Wn);

    // stage dup array: 45 rows x 55 dwords; dword i = (bf16 x[i], bf16 x[i+1]); sym pad
    for (int k = tid; k < DUPR * DUP_S; k += 256) {
        int j = k / DUP_S, i = k - j * DUP_S;
        int gy = gy0 - 6 + j;
        gy = (gy < 0) ? (-1 - gy) : ((gy > 255) ? (511 - gy) : gy);
        int gx0 = tx0 - 6 + i, gx1 = gx0 + 1;
        gx0 = (gx0 < 0) ? (-1 - gx0) : ((gx0 > 255) ? (511 - gx0) : gx0);
        gx1 = (gx1 < 0) ? (-1 - gx1) : ((gx1 > 255) ? (511 - gx1) : gx1);
        float x0 = img[gy * Wn + gx0];
        float x1 = img[gy * Wn + gx1];
        s_dup[j * DUP_S + i] = (unsigned int)f2bf(x0) | ((unsigned int)f2bf(x1) << 16);
    }
    // CRITICAL: zero ALL of s_a. Raw blocks 6..7 (f=48..63) are read as MFMA
    // B-operands but never written; A2 weights there are zero, but
    // 0 * (uninitialized LDS == Inf/NaN bf16 pattern) = NaN (round-8 failure).
    {
        unsigned int* sa32 = (unsigned int*)s_a;
        for (int k = tid; k < 2048; k += 256) sa32[k] = 0u;
    }
    __syncthreads();

    // constant weight fragments
    const uint4* frg = (const uint4*)(ws + WS_FRG);
    short8 Afz[3][2], Afc[4][2];
    #pragma unroll
    for (int mt = 0; mt < 3; ++mt)
        #pragma unroll
        for (int kt = 0; kt < 2; ++kt)
            Afz[mt][kt] = __builtin_bit_cast(short8, frg[(mt * 2 + kt) * 64 + lane]);
    #pragma unroll
    for (int mt = 0; mt < 4; ++mt)
        #pragma unroll
        for (int kt = 0; kt < 2; ++kt)
            Afc[mt][kt] = __builtin_bit_cast(short8, frg[(6 + mt * 2 + kt) * 64 + lane]);

    const unsigned short* tab = (const unsigned short*)(ws + WS_TABB);
    const int fq = q4 * TAB_S;
    unsigned short* sa = s_a[wv];
    unsigned short* c2w = s_c2[wv];
    unsigned int* c2d = (unsigned int*)c2w;
    int wOff[3], rOff[2];
    #pragma unroll
    for (int mt = 0; mt < 3; ++mt)
        wOff[mt] = l15 * 64 + (((2 * mt + (quad >> 1)) ^ (l15 & 7)) * 8) + (quad & 1) * 4;
    #pragma unroll
    for (int kt = 0; kt < 2; ++kt)
        rOff[kt] = l15 * 64 + (((4 * kt + quad) ^ (l15 & 7)) * 8);

    const int A0 = wv * 8;
    float w[4] = {0.f, 0.f, 0.f, 0.f};
    float rsq = 0.f;

    auto subiter = [&](int i, bool even) {
        const int aIdx = A0 + i;
        const int gyz = gy0 - 3 + aIdx;
        const bool vy = ((unsigned)gyz < (unsigned)Hn);

        #pragma unroll
        for (int nt = 0; nt < 3; ++nt) {
            const int nt16 = nt * 16;
            const int ax = l15 + nt16;
            const unsigned* dp0 = &s_dup[(aIdx + quad) * DUP_S + l15 + nt16];
            const unsigned* dp1 = dp0 + 4 * DUP_S;
            short8 B0 = __builtin_bit_cast(short8, make_uint4(dp0[0], dp0[2], dp0[4], dp0[6]));
            short8 B1 = __builtin_bit_cast(short8, make_uint4(dp1[0], dp1[2], dp1[4], dp1[6]));
            const unsigned msk = (vy && ((unsigned)(tx0 - 3 + ax) < (unsigned)Wn))
                                 ? 0xFFFFFFFFu : 0u;
            #pragma unroll
            for (int mt = 0; mt < 3; ++mt) {
                f32x4 z = {0.f, 0.f, 0.f, 0.f};
                z = __builtin_amdgcn_mfma_f32_16x16x32_bf16(Afz[mt][0], B0, z, 0, 0, 0);
                z = __builtin_amdgcn_mfma_f32_16x16x32_bf16(Afz[mt][1], B1, z, 0, 0, 0);
                unsigned g[4];
                #pragma unroll
                for (int r = 0; r < 4; ++r) {
                    float tt = fmaf(z[r], 40.0f, 4000.5f);
                    tt = fminf(fmaxf(tt, 0.f), 8000.f);
                    g[r] = tab[fq + (mt * 16 + r) * TAB_S + (int)tt];
                }
                unsigned lo = (g[0] | (g[1] << 16)) & msk;
                unsigned hi = (g[2] | (g[3] << 16)) & msk;
                *(uint2*)&sa[wOff[mt]] = make_uint2(lo, hi);
            }
            short8 B20 = *(const short8*)&sa[rOff[0]];
            short8 B21 = *(const short8*)&sa[rOff[1]];
            f32x4 d2[4];
            #pragma unroll
            for (int mt = 0; mt < 4; ++mt) {
                f32x4 c0 = {0.f, 0.f, 0.f, 0.f};
                c0 = __builtin_amdgcn_mfma_f32_16x16x32_bf16(Afc[mt][0], B20, c0, 0, 0, 0);
                c0 = __builtin_amdgcn_mfma_f32_16x16x32_bf16(Afc[mt][1], B21, c0, 0, 0, 0);
                d2[mt] = c0;
            }
            // C2 stores: lane's rows m = mt*16+q4 .. +3 -> packed bf16 pairs, 2 b32 per mt
            const int rowdw = ax * C2DW;
            #pragma unroll
            for (int mt = 0; mt < 4; ++mt) {
                unsigned lo = (unsigned)f2bf(d2[mt][0]) | ((unsigned)f2bf(d2[mt][1]) << 16);
                unsigned hi = (unsigned)f2bf(d2[mt][2]) | ((unsigned)f2bf(d2[mt][3]) << 16);
                const int cd = rowdw + mt * 8 + 2 * quad;
                if (mt < 3) {
                    c2d[cd] = lo;
                    c2d[cd + 1] = hi;
                } else if (quad < 2) {    // m=56..63 junk rows; cols would overflow stride
                    c2d[cd] = lo;
                    c2d[cd + 1] = hi;
                }
            }
        }

        // ---- q-gather into register window ----
        const bool laneE = even ? (hl == 0) : (hl != 0);
        #pragma unroll
        for (int j = 0; j < 4; ++j) {
            const int pe = 2 * j, po = 2 * j + 1;
            const bool liveE = (pe <= i) && (pe >= i - 7);
            const bool liveO = (j < 3) && (po <= i) && (po >= i - 7);
            if (liveE || liveO) {
                int psel = laneE ? pe : po;
                if (!liveO) psel = pe;
                if (!liveE) psel = po;
                const int p8 = psel * 8;
                float acc = 0.f;
                #pragma unroll
                for (int q = 0; q < 7; ++q) {
                    unsigned short u = c2w[(OX + q) * C2ST + p8 + q];
                    acc += __builtin_bit_cast(float, ((unsigned)u) << 16);
                }
                if (liveE) w[3 - j] += laneE ? acc : 0.f;
                if (liveO) w[2 - j] += laneE ? 0.f : acc;
            }
        }

        // ---- close one output row + shift window ----
        if (i >= 6) {
            const int gyO = gy0 + A0 + i - 6;
            const int o = gyO * Wn + tx0 + OX;
            if (laneE) {
                float r = img[o] - w[0] - netb[o];
                rb[o] = r;
                rsq += r * r;
            }
        }
        w[0] = laneE ? w[1] : w[0];
        w[1] = laneE ? w[2] : w[1];
        w[2] = laneE ? w[3] : w[2];
        w[3] = laneE ? 0.f : w[3];
    };

    #pragma unroll 1
    for (int mi = 0; mi < 7; ++mi) {
        subiter(2 * mi, true);
        subiter(2 * mi + 1, false);
    }

    rsq = waveReduceSum(rsq);
    if (lane == 0) s_red[wv] = rsq;
    __syncthreads();
    if (tid == 0) atomicAdd(&ws[WS_SUMSQ + bz], s_red[0] + s_red[1] + s_red[2] + s_red[3]);
}

__global__ __launch_bounds__(256) void finalize_kernel(const float* __restrict__ net,
                                                       const float* __restrict__ stdn,
                                                       const float* __restrict__ alpha,
                                                       const float* __restrict__ ws,
                                                       float* __restrict__ out) {
    const int b = blockIdx.y;
    const float sum = ws[WS_SUMSQ + b];
    const float k = __expf(alpha[0]) * stdn[b] * 256.0f;
    const float nr = sqrtf(sum);
    const float scale = fminf(1.0f, k / (nr + 1e-12f));
    const int base = b * (Hn * Wn) + (blockIdx.x * 256 + threadIdx.x) * 4;
    float4 rv = *(const float4*)(out + base);
    const float4 nv = *(const float4*)(net + base);
    float4 o;
    o.x = fmaf(rv.x, scale, nv.x);
    o.y = fmaf(rv.y, scale, nv.y);
    o.z = fmaf(rv.z, scale, nv.z);
    o.w = fmaf(rv.w, scale, nv.w);
    *(float4*)(out + base) = o;
}

extern "C" void kernel_launch(void* const* d_in, const int* in_sizes, int n_in,
                              void* d_out, int out_size, void* d_ws, size_t ws_size,
                              hipStream_t stream) {
    const float* input = (const float*)d_in[0];
    const float* stdn  = (const float*)d_in[1];
    const float* net   = (const float*)d_in[3];
    const float* cw    = (const float*)d_in[4];
    const float* sf    = (const float*)d_in[5];
    const float* alpha = (const float*)d_in[6];
    const float* rw    = (const float*)d_in[7];
    const float* rc    = (const float*)d_in[8];
    float* out = (float*)d_out;
    float* ws  = (float*)d_ws;

    setup_kernel<<<dim3(1 + 48 * 32), 256, 0, stream>>>(cw, sf, rw, rc, ws);
    fused_kernel<<<dim3(Wn / TW, Hn / STRIP, Bn), 256, 0, stream>>>(input, net, ws, out);
    finalize_kernel<<<dim3(64, Bn), 256, 0, stream>>>(net, stdn, alpha, ws, out);
}